// Round 3
// baseline (1538.261 us; speedup 1.0000x reference)
//
#include <hip/hip_runtime.h>
#include <math.h>

// ---- problem constants ----
#define B_      32
#define HH      56
#define WW_     56
#define DIM     192
#define WS_     7
#define SHIFT_  3
#define HEADS   6
#define HDIM    32
#define NTOK    49          // WS*WS
#define NWIN    64          // (H/WS)*(W/WS)
#define HIDDEN  768
#define MTOT    (B_*HH*WW_) // 100352 tokens
#define CHUNK_M 25088       // MTOT/4 for MLP chunking
#define EPS_    1e-5f
#define SCALE_  0.17677669529663687f  // 1/sqrt(32)

typedef unsigned short u16;

__device__ __forceinline__ float bf2f(u16 u) {
    union { unsigned int i; float f; } c; c.i = ((unsigned int)u) << 16; return c.f;
}
__device__ __forceinline__ u16 f2bf(float f) {
    union { float f; unsigned int i; } c; c.f = f;
    unsigned int x = c.i;
    return (u16)((x + 0x7FFFu + ((x >> 16) & 1u)) >> 16);  // RNE (finite values)
}

// ---------------- wave reduce ----------------
__device__ __forceinline__ float wave_sum(float v) {
    #pragma unroll
    for (int off = 32; off > 0; off >>= 1) v += __shfl_xor(v, off, 64);
    return v;
}

// ---------------- LN1 + roll(-3,-3) + window partition (fp32 in, bf16 out) ----------------
__global__ __launch_bounds__(256) void ln1_window_kernel(
        const float* __restrict__ x, const float* __restrict__ g,
        const float* __restrict__ b, u16* __restrict__ out) {
    int row  = blockIdx.x * 4 + (threadIdx.x >> 6);
    int lane = threadIdx.x & 63;
    int win = row / NTOK;
    int n   = row - win * NTOK;
    int bb  = win >> 6;
    int wl  = win & 63;
    int hi  = (wl >> 3) * WS_ + n / WS_;
    int hj  = (wl & 7) * WS_ + n % WS_;
    int sh = hi + SHIFT_; if (sh >= HH) sh -= HH;
    int sw = hj + SHIFT_; if (sw >= WW_) sw -= WW_;
    const float* xr = x + ((size_t)(bb * HH * WW_ + sh * WW_ + sw)) * DIM;
    float v0 = xr[lane], v1 = xr[lane + 64], v2 = xr[lane + 128];
    float s  = wave_sum(v0 + v1 + v2);
    float sq = wave_sum(v0 * v0 + v1 * v1 + v2 * v2);
    float mu  = s * (1.0f / DIM);
    float var = sq * (1.0f / DIM) - mu * mu;
    float r = rsqrtf(var + EPS_);
    u16* orow = out + (size_t)row * DIM;
    orow[lane]       = f2bf((v0 - mu) * r * g[lane]       + b[lane]);
    orow[lane + 64]  = f2bf((v1 - mu) * r * g[lane + 64]  + b[lane + 64]);
    orow[lane + 128] = f2bf((v2 - mu) * r * g[lane + 128] + b[lane + 128]);
}

// ---------------- LN2: fp32 in (residual stream), bf16 out ----------------
__global__ __launch_bounds__(256) void ln2_kernel(
        const float* __restrict__ x, const float* __restrict__ g,
        const float* __restrict__ b, u16* __restrict__ out) {
    int row  = blockIdx.x * 4 + (threadIdx.x >> 6);
    int lane = threadIdx.x & 63;
    const float* xr = x + (size_t)row * DIM;
    float v0 = xr[lane], v1 = xr[lane + 64], v2 = xr[lane + 128];
    float s  = wave_sum(v0 + v1 + v2);
    float sq = wave_sum(v0 * v0 + v1 * v1 + v2 * v2);
    float mu  = s * (1.0f / DIM);
    float var = sq * (1.0f / DIM) - mu * mu;
    float r = rsqrtf(var + EPS_);
    u16* orow = out + (size_t)row * DIM;
    orow[lane]       = f2bf((v0 - mu) * r * g[lane]       + b[lane]);
    orow[lane + 64]  = f2bf((v1 - mu) * r * g[lane + 64]  + b[lane + 64]);
    orow[lane + 128] = f2bf((v2 - mu) * r * g[lane + 128] + b[lane + 128]);
}

// ------- tiled GEMM: A bf16 (staged activations), B fp32 (weights), fp32 acc -------
// 64x64 tile, BK=16, 4x4 per thread
__device__ __forceinline__ void gemm_tile(
        const u16* __restrict__ A, const float* __restrict__ Bw,
        int K, int N, int m0, int n0, float (&acc)[4][4]) {
    __shared__ float As[16][64];
    __shared__ float Bs[16][64];
    int tid = threadIdx.x;
    int tx = tid & 15, ty = tid >> 4;
    int ar = tid >> 2, ac = (tid & 3) * 4;   // A-tile: row, k quad
    int bk = tid >> 4, bc = (tid & 15) * 4;  // B-tile: k-row, col quad
    #pragma unroll
    for (int i = 0; i < 4; i++)
        #pragma unroll
        for (int j = 0; j < 4; j++) acc[i][j] = 0.0f;

    for (int k0 = 0; k0 < K; k0 += 16) {
        ushort4 av = *(const ushort4*)(A + (size_t)(m0 + ar) * K + k0 + ac);
        float4  bv = *(const float4*)(Bw + (size_t)(k0 + bk) * N + n0 + bc);
        __syncthreads();
        As[ac + 0][ar] = bf2f(av.x); As[ac + 1][ar] = bf2f(av.y);
        As[ac + 2][ar] = bf2f(av.z); As[ac + 3][ar] = bf2f(av.w);
        *(float4*)&Bs[bk][bc] = bv;
        __syncthreads();
        #pragma unroll
        for (int k = 0; k < 16; k++) {
            float a0 = As[k][ty * 4 + 0], a1 = As[k][ty * 4 + 1];
            float a2 = As[k][ty * 4 + 2], a3 = As[k][ty * 4 + 3];
            float b0 = Bs[k][tx * 4 + 0], b1 = Bs[k][tx * 4 + 1];
            float b2 = Bs[k][tx * 4 + 2], b3 = Bs[k][tx * 4 + 3];
            acc[0][0] += a0 * b0; acc[0][1] += a0 * b1; acc[0][2] += a0 * b2; acc[0][3] += a0 * b3;
            acc[1][0] += a1 * b0; acc[1][1] += a1 * b1; acc[1][2] += a1 * b2; acc[1][3] += a1 * b3;
            acc[2][0] += a2 * b0; acc[2][1] += a2 * b1; acc[2][2] += a2 * b2; acc[2][3] += a2 * b3;
            acc[3][0] += a3 * b0; acc[3][1] += a3 * b1; acc[3][2] += a3 * b2; acc[3][3] += a3 * b3;
        }
    }
}

// ---------------- GEMM: QKV projection, scatter to (win, head, n, d), bf16 out ----------------
__global__ __launch_bounds__(256) void gemm_qkv_kernel(
        const u16* __restrict__ hwin, const float* __restrict__ qkv_w,
        const float* __restrict__ qkv_b,
        u16* __restrict__ q, u16* __restrict__ k, u16* __restrict__ v) {
    float acc[4][4];
    int m0 = blockIdx.y * 64, n0 = blockIdx.x * 64;
    gemm_tile(hwin, qkv_w, DIM, 3 * DIM, m0, n0, acc);
    int tx = threadIdx.x & 15, ty = threadIdx.x >> 4;
    #pragma unroll
    for (int i = 0; i < 4; i++) {
        int row = m0 + ty * 4 + i;
        int win = row / NTOK;
        int n   = row - win * NTOK;
        #pragma unroll
        for (int j = 0; j < 4; j++) {
            int col = n0 + tx * 4 + j;
            float val = acc[i][j] + qkv_b[col];
            int which = col / DIM;
            int rem   = col - which * DIM;
            int head  = rem >> 5;
            int d     = rem & 31;
            u16* dst = (which == 0) ? q : ((which == 1) ? k : v);
            dst[(((size_t)win * HEADS + head) * NTOK + n) * HDIM + d] = f2bf(val);
        }
    }
}

// ---------------- attention: one 64-thread block per (window, head) ----------------
__global__ __launch_bounds__(64) void attn_kernel(
        const u16* __restrict__ q, const u16* __restrict__ k,
        const u16* __restrict__ v, const float* __restrict__ rel_table,
        const float* __restrict__ mask, u16* __restrict__ attn_out) {
    int wh   = blockIdx.x;          // win*HEADS + head
    int win  = wh / HEADS;
    int head = wh - win * HEADS;
    int wl   = win & 63;
    __shared__ float Ksh[NTOK][HDIM];
    __shared__ float Vsh[NTOK][HDIM];
    int tid = threadIdx.x;
    const u16* kbase = k + (size_t)wh * NTOK * HDIM;
    const u16* vbase = v + (size_t)wh * NTOK * HDIM;
    for (int t = tid; t < NTOK * HDIM; t += 64) {
        (&Ksh[0][0])[t] = bf2f(kbase[t]);
        (&Vsh[0][0])[t] = bf2f(vbase[t]);
    }
    __syncthreads();
    if (tid < NTOK) {
        int qi = tid;
        float qreg[HDIM];
        const u16* qb = q + ((size_t)wh * NTOK + qi) * HDIM;
        #pragma unroll
        for (int d = 0; d < HDIM; d++) qreg[d] = bf2f(qb[d]);
        int qr = qi / WS_, qc = qi % WS_;
        const float* mrow = mask + ((size_t)wl * NTOK + qi) * NTOK;
        float scores[NTOK];
        float mx = -1e30f;
        for (int m = 0; m < NTOK; m++) {
            float s = 0.0f;
            #pragma unroll
            for (int d = 0; d < HDIM; d++) s += qreg[d] * Ksh[m][d];
            int kr = m / WS_, kc = m % WS_;
            int idx = (qr - kr + 6) * 13 + (qc - kc + 6);
            s = s * SCALE_ + rel_table[idx * HEADS + head] + mrow[m];
            scores[m] = s;
            mx = fmaxf(mx, s);
        }
        float sum = 0.0f;
        for (int m = 0; m < NTOK; m++) { float p = __expf(scores[m] - mx); scores[m] = p; sum += p; }
        float inv = 1.0f / sum;
        float o[HDIM];
        #pragma unroll
        for (int d = 0; d < HDIM; d++) o[d] = 0.0f;
        for (int m = 0; m < NTOK; m++) {
            float p = scores[m];
            #pragma unroll
            for (int d = 0; d < HDIM; d++) o[d] += p * Vsh[m][d];
        }
        u16* ob = attn_out + ((size_t)win * NTOK + qi) * DIM + head * HDIM;
        #pragma unroll
        for (int d = 0; d < HDIM; d++) ob[d] = f2bf(o[d] * inv);
    }
}

// ------- GEMM: proj + window reverse + roll(+3,+3) + residual(fp32 x) -> fp32 x1 -------
__global__ __launch_bounds__(256) void gemm_proj_kernel(
        const u16* __restrict__ attn_o, const float* __restrict__ proj_w,
        const float* __restrict__ proj_b, const float* __restrict__ x,
        float* __restrict__ x1) {
    float acc[4][4];
    int m0 = blockIdx.y * 64, n0 = blockIdx.x * 64;
    gemm_tile(attn_o, proj_w, DIM, DIM, m0, n0, acc);
    int tx = threadIdx.x & 15, ty = threadIdx.x >> 4;
    #pragma unroll
    for (int i = 0; i < 4; i++) {
        int row = m0 + ty * 4 + i;
        int win = row / NTOK;
        int n   = row - win * NTOK;
        int bb  = win >> 6;
        int wl  = win & 63;
        int hi = (wl >> 3) * WS_ + n / WS_;
        int hj = (wl & 7) * WS_ + n % WS_;
        int dh = hi + SHIFT_; if (dh >= HH) dh -= HH;
        int dw = hj + SHIFT_; if (dw >= WW_) dw -= WW_;
        size_t tok = (size_t)(bb * HH * WW_ + dh * WW_ + dw);
        #pragma unroll
        for (int j = 0; j < 4; j++) {
            int col = n0 + tx * 4 + j;
            x1[tok * DIM + col] = x[tok * DIM + col] + acc[i][j] + proj_b[col];
        }
    }
}

// ---------------- GEMM: FC1 + exact GELU (bf16 out) ----------------
__global__ __launch_bounds__(256) void gemm_fc1_kernel(
        const u16* __restrict__ h2, const float* __restrict__ fc1_w,
        const float* __restrict__ fc1_b, u16* __restrict__ fc1_out) {
    float acc[4][4];
    int m0 = blockIdx.y * 64, n0 = blockIdx.x * 64;
    gemm_tile(h2, fc1_w, DIM, HIDDEN, m0, n0, acc);
    int tx = threadIdx.x & 15, ty = threadIdx.x >> 4;
    #pragma unroll
    for (int i = 0; i < 4; i++) {
        size_t row = (size_t)(m0 + ty * 4 + i);
        #pragma unroll
        for (int j = 0; j < 4; j++) {
            int col = n0 + tx * 4 + j;
            float val = acc[i][j] + fc1_b[col];
            float gel = 0.5f * val * (1.0f + erff(val * 0.70710678118f));
            fc1_out[row * HIDDEN + col] = f2bf(gel);
        }
    }
}

// ---------------- GEMM: FC2 + residual(fp32 x1) -> fp32 out ----------------
__global__ __launch_bounds__(256) void gemm_fc2_kernel(
        const u16* __restrict__ fc1_out, const float* __restrict__ fc2_w,
        const float* __restrict__ fc2_b, const float* __restrict__ x1,
        float* __restrict__ out, int row_off) {
    float acc[4][4];
    int m0 = blockIdx.y * 64, n0 = blockIdx.x * 64;
    gemm_tile(fc1_out, fc2_w, HIDDEN, DIM, m0, n0, acc);
    int tx = threadIdx.x & 15, ty = threadIdx.x >> 4;
    #pragma unroll
    for (int i = 0; i < 4; i++) {
        size_t grow = (size_t)(row_off + m0 + ty * 4 + i);
        #pragma unroll
        for (int j = 0; j < 4; j++) {
            int col = n0 + tx * 4 + j;
            out[grow * DIM + col] = x1[grow * DIM + col] + acc[i][j] + fc2_b[col];
        }
    }
}

extern "C" void kernel_launch(void* const* d_in, const int* in_sizes, int n_in,
                              void* d_out, int out_size, void* d_ws, size_t ws_size,
                              hipStream_t stream) {
    const float* x         = (const float*)d_in[0];
    const float* g1        = (const float*)d_in[1];
    const float* b1        = (const float*)d_in[2];
    const float* qkv_w     = (const float*)d_in[3];
    const float* qkv_b     = (const float*)d_in[4];
    const float* proj_w    = (const float*)d_in[5];
    const float* proj_b    = (const float*)d_in[6];
    const float* rel_table = (const float*)d_in[7];
    const float* g2        = (const float*)d_in[8];
    const float* b2        = (const float*)d_in[9];
    const float* fc1_w     = (const float*)d_in[10];
    const float* fc1_b     = (const float*)d_in[11];
    const float* fc2_w     = (const float*)d_in[12];
    const float* fc2_b     = (const float*)d_in[13];
    const float* attn_mask = (const float*)d_in[14];
    float* out = (float*)d_out;

    const size_t S = (size_t)MTOT * DIM;   // 19,267,584 elements
    u16* wsu = (u16*)d_ws;
    // byte layout (S elements each; 2B for bf16, 4B for fp32). Peak = 10S bytes = 193 MB.
    u16*   hwin    = wsu;                  // bytes [0,2S)    LN1/LN2 out (bf16)
    u16*   qb      = wsu + S;              // bytes [2S,4S)
    u16*   kb      = wsu + 2 * S;          // bytes [4S,6S)
    u16*   vb      = wsu + 3 * S;          // bytes [6S,8S)
    u16*   ao      = wsu + 4 * S;          // bytes [8S,10S)  attn out (bf16)
    float* x1      = (float*)(wsu + 2 * S);// bytes [4S,8S)   fp32 residual, overlays k/v (dead)
    u16*   fc1_buf = wsu + S;              // bytes [2S,4S)   MLP chunk (25088x768 bf16 == S), overlays q

    ln1_window_kernel<<<MTOT / 4, 256, 0, stream>>>(x, g1, b1, hwin);
    gemm_qkv_kernel<<<dim3(9, MTOT / 64), 256, 0, stream>>>(hwin, qkv_w, qkv_b, qb, kb, vb);
    attn_kernel<<<B_ * NWIN * HEADS, 64, 0, stream>>>(qb, kb, vb, rel_table, attn_mask, ao);
    gemm_proj_kernel<<<dim3(3, MTOT / 64), 256, 0, stream>>>(ao, proj_w, proj_b, x, x1);
    ln2_kernel<<<MTOT / 4, 256, 0, stream>>>(x1, g2, b2, hwin);
    for (int c = 0; c < 4; c++) {
        const u16* h2c = hwin + (size_t)c * CHUNK_M * DIM;
        gemm_fc1_kernel<<<dim3(12, CHUNK_M / 64), 256, 0, stream>>>(h2c, fc1_w, fc1_b, fc1_buf);
        gemm_fc2_kernel<<<dim3(3, CHUNK_M / 64), 256, 0, stream>>>(fc1_buf, fc2_w, fc2_b, x1,
                                                                   out, c * CHUNK_M);
    }
}

// Round 4
// 1071.759 us; speedup vs baseline: 1.4353x; 1.4353x over previous
//
#include <hip/hip_runtime.h>
#include <math.h>

// ---- problem constants ----
#define B_      32
#define HH      56
#define WW_     56
#define DIM     192
#define WS_     7
#define SHIFT_  3
#define HEADS   6
#define HDIM    32
#define NTOK    49          // WS*WS
#define NWIN    64          // (H/WS)*(W/WS)
#define HIDDEN  768
#define MTOT    (B_*HH*WW_) // 100352 tokens
#define CHUNK_M 25088       // MTOT/4 for MLP chunking
#define EPS_    1e-5f
#define SCALE_  0.17677669529663687f  // 1/sqrt(32)

// GEMM tiling
#define BM 256
#define BN 64
#define BK 32
#define LDK 40   // padded LDS K-stride (2-way bank conflicts only)

typedef unsigned short u16;
typedef __bf16 bf16_t;
typedef __attribute__((ext_vector_type(8))) __bf16 bf16x8;
typedef __attribute__((ext_vector_type(4))) float f32x4;

__device__ __forceinline__ float bf2f(u16 u) {
    union { unsigned int i; float f; } c; c.i = ((unsigned int)u) << 16; return c.f;
}
__device__ __forceinline__ u16 f2bf(float f) {
    union { float f; unsigned int i; } c; c.f = f;
    unsigned int x = c.i;
    return (u16)((x + 0x7FFFu + ((x >> 16) & 1u)) >> 16);  // RNE (finite values)
}

// ---------------- wave reduce ----------------
__device__ __forceinline__ float wave_sum(float v) {
    #pragma unroll
    for (int off = 32; off > 0; off >>= 1) v += __shfl_xor(v, off, 64);
    return v;
}

// ---------------- weight convert+transpose: Wt[n*K+k] = bf16(W[k*N+n]) ----------------
__global__ __launch_bounds__(256) void transpose_w_kernel(
        const float* __restrict__ W, u16* __restrict__ Wt, int K, int N) {
    int idx = blockIdx.x * 256 + threadIdx.x;
    if (idx >= K * N) return;
    int n = idx / K, kk = idx - n * K;
    Wt[idx] = f2bf(W[(size_t)kk * N + n]);
}

// ---------------- LN1 + roll(-3,-3) + window partition (fp32 in, bf16 out) ----------------
__global__ __launch_bounds__(256) void ln1_window_kernel(
        const float* __restrict__ x, const float* __restrict__ g,
        const float* __restrict__ b, u16* __restrict__ out) {
    int row  = blockIdx.x * 4 + (threadIdx.x >> 6);
    int lane = threadIdx.x & 63;
    int win = row / NTOK;
    int n   = row - win * NTOK;
    int bb  = win >> 6;
    int wl  = win & 63;
    int hi  = (wl >> 3) * WS_ + n / WS_;
    int hj  = (wl & 7) * WS_ + n % WS_;
    int sh = hi + SHIFT_; if (sh >= HH) sh -= HH;
    int sw = hj + SHIFT_; if (sw >= WW_) sw -= WW_;
    const float* xr = x + ((size_t)(bb * HH * WW_ + sh * WW_ + sw)) * DIM;
    float v0 = xr[lane], v1 = xr[lane + 64], v2 = xr[lane + 128];
    float s  = wave_sum(v0 + v1 + v2);
    float sq = wave_sum(v0 * v0 + v1 * v1 + v2 * v2);
    float mu  = s * (1.0f / DIM);
    float var = sq * (1.0f / DIM) - mu * mu;
    float r = rsqrtf(var + EPS_);
    u16* orow = out + (size_t)row * DIM;
    orow[lane]       = f2bf((v0 - mu) * r * g[lane]       + b[lane]);
    orow[lane + 64]  = f2bf((v1 - mu) * r * g[lane + 64]  + b[lane + 64]);
    orow[lane + 128] = f2bf((v2 - mu) * r * g[lane + 128] + b[lane + 128]);
}

// ---------------- LN2: fp32 in (residual stream), bf16 out ----------------
__global__ __launch_bounds__(256) void ln2_kernel(
        const float* __restrict__ x, const float* __restrict__ g,
        const float* __restrict__ b, u16* __restrict__ out) {
    int row  = blockIdx.x * 4 + (threadIdx.x >> 6);
    int lane = threadIdx.x & 63;
    const float* xr = x + (size_t)row * DIM;
    float v0 = xr[lane], v1 = xr[lane + 64], v2 = xr[lane + 128];
    float s  = wave_sum(v0 + v1 + v2);
    float sq = wave_sum(v0 * v0 + v1 * v1 + v2 * v2);
    float mu  = s * (1.0f / DIM);
    float var = sq * (1.0f / DIM) - mu * mu;
    float r = rsqrtf(var + EPS_);
    u16* orow = out + (size_t)row * DIM;
    orow[lane]       = f2bf((v0 - mu) * r * g[lane]       + b[lane]);
    orow[lane + 64]  = f2bf((v1 - mu) * r * g[lane + 64]  + b[lane + 64]);
    orow[lane + 128] = f2bf((v2 - mu) * r * g[lane + 128] + b[lane + 128]);
}

// ---------------- MFMA GEMM core ----------------
// A: [M x K] bf16 row-major (u16), Bt: [N x K] bf16 row-major (pre-transposed weights)
// Tile BM=256 x BN=64, BK=32; 4 waves, each 64 rows x 64 cols as 4x4 16x16 mfma tiles.
struct GemmSmem {
    u16 As[BM][LDK];  // 20480 B
    u16 Bs[BN][LDK];  //  5120 B
};

template<int K>
__device__ __forceinline__ void gemm_core(
        const u16* __restrict__ A, const u16* __restrict__ Bt,
        int m0, int n0, GemmSmem& sm, f32x4 (&acc)[4][4]) {
    int tid  = threadIdx.x;
    int lane = tid & 63;
    int w    = tid >> 6;
    int lrow = lane & 15;
    int lq   = lane >> 4;

    #pragma unroll
    for (int i = 0; i < 4; i++)
        #pragma unroll
        for (int j = 0; j < 4; j++) acc[i][j] = (f32x4){0.f, 0.f, 0.f, 0.f};

    int bn = tid >> 2, bko = (tid & 3) * 8;

    for (int k0 = 0; k0 < K; k0 += BK) {
        uint4 a_ld[4];
        #pragma unroll
        for (int i = 0; i < 4; i++) {
            int c = tid + i * 256;
            int m = c >> 2, ko = (c & 3) * 8;
            a_ld[i] = *(const uint4*)(A + (size_t)(m0 + m) * K + k0 + ko);
        }
        uint4 b_ld = *(const uint4*)(Bt + (size_t)(n0 + bn) * K + k0 + bko);
        __syncthreads();
        #pragma unroll
        for (int i = 0; i < 4; i++) {
            int c = tid + i * 256;
            int m = c >> 2, ko = (c & 3) * 8;
            *(uint4*)&sm.As[m][ko] = a_ld[i];
        }
        *(uint4*)&sm.Bs[bn][bko] = b_ld;
        __syncthreads();
        bf16x8 aF[4], bF[4];
        #pragma unroll
        for (int mt = 0; mt < 4; mt++)
            aF[mt] = *(const bf16x8*)&sm.As[w * 64 + mt * 16 + lrow][lq * 8];
        #pragma unroll
        for (int nt = 0; nt < 4; nt++)
            bF[nt] = *(const bf16x8*)&sm.Bs[nt * 16 + lrow][lq * 8];
        #pragma unroll
        for (int mt = 0; mt < 4; mt++)
            #pragma unroll
            for (int nt = 0; nt < 4; nt++)
                acc[mt][nt] = __builtin_amdgcn_mfma_f32_16x16x32_bf16(
                    aF[mt], bF[nt], acc[mt][nt], 0, 0, 0);
    }
}

// ---------------- GEMM: QKV projection, scatter to (win, head, n, d) ----------------
__global__ __launch_bounds__(256) void gemm_qkv_mfma(
        const u16* __restrict__ Aact, const u16* __restrict__ Bt,
        const float* __restrict__ bias,
        u16* __restrict__ q, u16* __restrict__ k, u16* __restrict__ v) {
    __shared__ GemmSmem sm;
    f32x4 acc[4][4];
    int m0 = blockIdx.y * BM, n0 = blockIdx.x * BN;
    gemm_core<DIM>(Aact, Bt, m0, n0, sm, acc);
    int lane = threadIdx.x & 63, w = threadIdx.x >> 6;
    int lrow = lane & 15, lq = lane >> 4;
    #pragma unroll
    for (int nt = 0; nt < 4; nt++) {
        int col = n0 + nt * 16 + lrow;
        float bv = bias[col];
        int which = col / DIM;
        int rem   = col - which * DIM;
        int head  = rem >> 5;
        int d     = rem & 31;
        u16* dst = (which == 0) ? q : ((which == 1) ? k : v);
        #pragma unroll
        for (int mt = 0; mt < 4; mt++)
            #pragma unroll
            for (int r = 0; r < 4; r++) {
                int row = m0 + w * 64 + mt * 16 + lq * 4 + r;
                int win = row / NTOK;
                int n   = row - win * NTOK;
                dst[(((size_t)win * HEADS + head) * NTOK + n) * HDIM + d] =
                    f2bf(acc[mt][nt][r] + bv);
            }
    }
}

// ------- GEMM: proj + window reverse + roll(+3,+3) + residual(fp32 x) -> fp32 x1 -------
__global__ __launch_bounds__(256) void gemm_proj_mfma(
        const u16* __restrict__ Aact, const u16* __restrict__ Bt,
        const float* __restrict__ bias, const float* __restrict__ x,
        float* __restrict__ x1) {
    __shared__ GemmSmem sm;
    f32x4 acc[4][4];
    int m0 = blockIdx.y * BM, n0 = blockIdx.x * BN;
    gemm_core<DIM>(Aact, Bt, m0, n0, sm, acc);
    int lane = threadIdx.x & 63, w = threadIdx.x >> 6;
    int lrow = lane & 15, lq = lane >> 4;
    #pragma unroll
    for (int mt = 0; mt < 4; mt++)
        #pragma unroll
        for (int r = 0; r < 4; r++) {
            int row = m0 + w * 64 + mt * 16 + lq * 4 + r;
            int win = row / NTOK;
            int n   = row - win * NTOK;
            int bb  = win >> 6;
            int wl  = win & 63;
            int hi = (wl >> 3) * WS_ + n / WS_;
            int hj = (wl & 7) * WS_ + n % WS_;
            int dh = hi + SHIFT_; if (dh >= HH) dh -= HH;
            int dw = hj + SHIFT_; if (dw >= WW_) dw -= WW_;
            size_t tok = (size_t)(bb * HH * WW_ + dh * WW_ + dw);
            #pragma unroll
            for (int nt = 0; nt < 4; nt++) {
                int col = n0 + nt * 16 + lrow;
                x1[tok * DIM + col] = x[tok * DIM + col] + acc[mt][nt][r] + bias[col];
            }
        }
}

// ---------------- GEMM: FC1 + exact GELU (bf16 out, chunk-relative rows) ----------------
__global__ __launch_bounds__(256) void gemm_fc1_mfma(
        const u16* __restrict__ Aact, const u16* __restrict__ Bt,
        const float* __restrict__ bias, u16* __restrict__ fc1_out) {
    __shared__ GemmSmem sm;
    f32x4 acc[4][4];
    int m0 = blockIdx.y * BM, n0 = blockIdx.x * BN;
    gemm_core<DIM>(Aact, Bt, m0, n0, sm, acc);
    int lane = threadIdx.x & 63, w = threadIdx.x >> 6;
    int lrow = lane & 15, lq = lane >> 4;
    #pragma unroll
    for (int nt = 0; nt < 4; nt++) {
        int col = n0 + nt * 16 + lrow;
        float bv = bias[col];
        #pragma unroll
        for (int mt = 0; mt < 4; mt++)
            #pragma unroll
            for (int r = 0; r < 4; r++) {
                size_t row = (size_t)(m0 + w * 64 + mt * 16 + lq * 4 + r);
                float val = acc[mt][nt][r] + bv;
                float gel = 0.5f * val * (1.0f + erff(val * 0.70710678118f));
                fc1_out[row * HIDDEN + col] = f2bf(gel);
            }
    }
}

// ---------------- GEMM: FC2 + residual(fp32 x1) -> fp32 out ----------------
__global__ __launch_bounds__(256) void gemm_fc2_mfma(
        const u16* __restrict__ Aact, const u16* __restrict__ Bt,
        const float* __restrict__ bias, const float* __restrict__ x1,
        float* __restrict__ out, int row_off) {
    __shared__ GemmSmem sm;
    f32x4 acc[4][4];
    int m0 = blockIdx.y * BM, n0 = blockIdx.x * BN;
    gemm_core<HIDDEN>(Aact, Bt, m0, n0, sm, acc);
    int lane = threadIdx.x & 63, w = threadIdx.x >> 6;
    int lrow = lane & 15, lq = lane >> 4;
    #pragma unroll
    for (int nt = 0; nt < 4; nt++) {
        int col = n0 + nt * 16 + lrow;
        float bv = bias[col];
        #pragma unroll
        for (int mt = 0; mt < 4; mt++)
            #pragma unroll
            for (int r = 0; r < 4; r++) {
                size_t grow = (size_t)(row_off + m0 + w * 64 + mt * 16 + lq * 4 + r);
                out[grow * DIM + col] = x1[grow * DIM + col] + acc[mt][nt][r] + bv;
            }
    }
}

// ---------------- attention: one 64-thread block per (window, head) ----------------
__global__ __launch_bounds__(64) void attn_kernel(
        const u16* __restrict__ q, const u16* __restrict__ k,
        const u16* __restrict__ v, const float* __restrict__ rel_table,
        const float* __restrict__ mask, u16* __restrict__ attn_out) {
    int wh   = blockIdx.x;          // win*HEADS + head
    int win  = wh / HEADS;
    int head = wh - win * HEADS;
    int wl   = win & 63;
    __shared__ float Ksh[NTOK][HDIM];
    __shared__ float Vsh[NTOK][HDIM];
    int tid = threadIdx.x;
    const u16* kbase = k + (size_t)wh * NTOK * HDIM;
    const u16* vbase = v + (size_t)wh * NTOK * HDIM;
    for (int t = tid; t < NTOK * HDIM; t += 64) {
        (&Ksh[0][0])[t] = bf2f(kbase[t]);
        (&Vsh[0][0])[t] = bf2f(vbase[t]);
    }
    __syncthreads();
    if (tid < NTOK) {
        int qi = tid;
        float qreg[HDIM];
        const u16* qb = q + ((size_t)wh * NTOK + qi) * HDIM;
        #pragma unroll
        for (int d = 0; d < HDIM; d++) qreg[d] = bf2f(qb[d]);
        int qr = qi / WS_, qc = qi % WS_;
        const float* mrow = mask + ((size_t)wl * NTOK + qi) * NTOK;
        float scores[NTOK];
        float mx = -1e30f;
        for (int m = 0; m < NTOK; m++) {
            float s = 0.0f;
            #pragma unroll
            for (int d = 0; d < HDIM; d++) s += qreg[d] * Ksh[m][d];
            int kr = m / WS_, kc = m % WS_;
            int idx = (qr - kr + 6) * 13 + (qc - kc + 6);
            s = s * SCALE_ + rel_table[idx * HEADS + head] + mrow[m];
            scores[m] = s;
            mx = fmaxf(mx, s);
        }
        float sum = 0.0f;
        for (int m = 0; m < NTOK; m++) { float p = __expf(scores[m] - mx); scores[m] = p; sum += p; }
        float inv = 1.0f / sum;
        float o[HDIM];
        #pragma unroll
        for (int d = 0; d < HDIM; d++) o[d] = 0.0f;
        for (int m = 0; m < NTOK; m++) {
            float p = scores[m];
            #pragma unroll
            for (int d = 0; d < HDIM; d++) o[d] += p * Vsh[m][d];
        }
        u16* ob = attn_out + ((size_t)win * NTOK + qi) * DIM + head * HDIM;
        #pragma unroll
        for (int d = 0; d < HDIM; d++) ob[d] = f2bf(o[d] * inv);
    }
}

extern "C" void kernel_launch(void* const* d_in, const int* in_sizes, int n_in,
                              void* d_out, int out_size, void* d_ws, size_t ws_size,
                              hipStream_t stream) {
    const float* x         = (const float*)d_in[0];
    const float* g1        = (const float*)d_in[1];
    const float* b1        = (const float*)d_in[2];
    const float* qkv_w     = (const float*)d_in[3];
    const float* qkv_b     = (const float*)d_in[4];
    const float* proj_w    = (const float*)d_in[5];
    const float* proj_b    = (const float*)d_in[6];
    const float* rel_table = (const float*)d_in[7];
    const float* g2        = (const float*)d_in[8];
    const float* b2        = (const float*)d_in[9];
    const float* fc1_w     = (const float*)d_in[10];
    const float* fc1_b     = (const float*)d_in[11];
    const float* fc2_w     = (const float*)d_in[12];
    const float* fc2_b     = (const float*)d_in[13];
    const float* attn_mask = (const float*)d_in[14];
    float* out = (float*)d_out;

    const size_t S = (size_t)MTOT * DIM;   // 19,267,584 elements
    u16* wsu = (u16*)d_ws;
    // byte layout, peak = 8S*2 + 0.85 MB ~= 155 MB (proven-safe bound: 193 MB)
    u16*   hwin    = wsu;                  // [0,2S)  LN1 out -> attn out -> LN2 out (sequential reuse)
    u16*   qb      = wsu + S;              // [2S,4S) q -> later fc1_buf
    u16*   kb      = wsu + 2 * S;          // [4S,6S)
    u16*   vb      = wsu + 3 * S;          // [6S,8S)
    u16*   ao      = hwin;                 // attn out overlays LN1 out (dead after QKV GEMM)
    float* x1      = (float*)(wsu + 2 * S);// [4S,8S) fp32 residual, overlays k/v (dead after attn)
    u16*   fc1_buf = qb;                   // MLP chunk (25088x768 bf16 == S u16), overlays q
    u16*   wT      = wsu + 4 * S;          // weights bf16, transposed [N][K]
    u16*   qkv_wT  = wT;                   // 576*192 = 110592
    u16*   proj_wT = wT + 110592;          // 192*192 =  36864
    u16*   fc1_wT  = wT + 147456;          // 768*192 = 147456
    u16*   fc2_wT  = wT + 294912;          // 192*768 = 147456

    transpose_w_kernel<<<(DIM * 3 * DIM + 255) / 256, 256, 0, stream>>>(qkv_w, qkv_wT, DIM, 3 * DIM);
    transpose_w_kernel<<<(DIM * DIM + 255) / 256, 256, 0, stream>>>(proj_w, proj_wT, DIM, DIM);
    transpose_w_kernel<<<(DIM * HIDDEN + 255) / 256, 256, 0, stream>>>(fc1_w, fc1_wT, DIM, HIDDEN);
    transpose_w_kernel<<<(HIDDEN * DIM + 255) / 256, 256, 0, stream>>>(fc2_w, fc2_wT, HIDDEN, DIM);

    ln1_window_kernel<<<MTOT / 4, 256, 0, stream>>>(x, g1, b1, hwin);
    gemm_qkv_mfma<<<dim3(9, MTOT / BM), 256, 0, stream>>>(hwin, qkv_wT, qkv_b, qb, kb, vb);
    attn_kernel<<<B_ * NWIN * HEADS, 64, 0, stream>>>(qb, kb, vb, rel_table, attn_mask, ao);
    gemm_proj_mfma<<<dim3(3, MTOT / BM), 256, 0, stream>>>(ao, proj_wT, proj_b, x, x1);
    ln2_kernel<<<MTOT / 4, 256, 0, stream>>>(x1, g2, b2, hwin);
    for (int c = 0; c < 4; c++) {
        const u16* h2c = hwin + (size_t)c * CHUNK_M * DIM;
        gemm_fc1_mfma<<<dim3(12, CHUNK_M / BM), 256, 0, stream>>>(h2c, fc1_wT, fc1_b, fc1_buf);
        gemm_fc2_mfma<<<dim3(3, CHUNK_M / BM), 256, 0, stream>>>(fc1_buf, fc2_wT, fc2_b, x1,
                                                                 out, c * CHUNK_M);
    }
}

// Round 5
// 1049.564 us; speedup vs baseline: 1.4656x; 1.0211x over previous
//
#include <hip/hip_runtime.h>
#include <math.h>

// ---- problem constants ----
#define B_      32
#define HH      56
#define WW_     56
#define DIM     192
#define WS_     7
#define SHIFT_  3
#define HEADS   6
#define HDIM    32
#define NTOK    49          // WS*WS
#define NWIN    64          // (H/WS)*(W/WS)
#define HIDDEN  768
#define MTOT    (B_*HH*WW_) // 100352 tokens
#define CHUNK_M 25088       // MTOT/4 for MLP chunking
#define EPS_    1e-5f
#define SCALE_  0.17677669529663687f  // 1/sqrt(32)

// GEMM tiling
#define BM 256
#define BN 64
#define BK 32
#define LDK 40   // padded LDS K-stride (2-way bank conflicts only)

// attention LDS strides (u16 units) — chosen for 16B alignment + bank spread
#define PLD 72   // P row stride: 72*2=144 B, %16==0
#define OLD 200  // O row stride: 200*2=400 B, %16==0

typedef unsigned short u16;
typedef __bf16 bf16_t;
typedef __attribute__((ext_vector_type(8))) __bf16 bf16x8;
typedef __attribute__((ext_vector_type(4))) float f32x4;

__device__ __forceinline__ float bf2f(u16 u) {
    union { unsigned int i; float f; } c; c.i = ((unsigned int)u) << 16; return c.f;
}
__device__ __forceinline__ u16 f2bf(float f) {
    union { float f; unsigned int i; } c; c.f = f;
    unsigned int x = c.i;
    return (u16)((x + 0x7FFFu + ((x >> 16) & 1u)) >> 16);  // RNE (finite values)
}

// ---------------- wave reduce ----------------
__device__ __forceinline__ float wave_sum(float v) {
    #pragma unroll
    for (int off = 32; off > 0; off >>= 1) v += __shfl_xor(v, off, 64);
    return v;
}

// ---------------- weight convert+transpose: Wt[n*K+k] = bf16(W[k*N+n]) ----------------
__global__ __launch_bounds__(256) void transpose_w_kernel(
        const float* __restrict__ W, u16* __restrict__ Wt, int K, int N) {
    int idx = blockIdx.x * 256 + threadIdx.x;
    if (idx >= K * N) return;
    int n = idx / K, kk = idx - n * K;
    Wt[idx] = f2bf(W[(size_t)kk * N + n]);
}

// ------- fused bias+mask table: tbl[((wl*6+head)*64+qi)*64+kj], pads = -1e30 -------
__global__ __launch_bounds__(256) void build_tbl_kernel(
        const float* __restrict__ rel_table, const float* __restrict__ mask,
        float* __restrict__ tbl) {
    int idx = blockIdx.x * 256 + threadIdx.x;   // < 64*6*4096
    int kj   = idx & 63;
    int qi   = (idx >> 6) & 63;
    int head = (idx >> 12) % 6;
    int wl   = idx / (6 << 12);
    float v;
    if (qi < NTOK && kj < NTOK) {
        int qr = qi / WS_, qc = qi % WS_;
        int kr = kj / WS_, kc = kj % WS_;
        int ri = (qr - kr + 6) * 13 + (qc - kc + 6);
        v = rel_table[ri * HEADS + head] + mask[((size_t)wl * NTOK + qi) * NTOK + kj];
    } else {
        v = -1e30f;
    }
    tbl[idx] = v;
}

// ---------------- LN1 + roll(-3,-3) + window partition (fp32 in, bf16 out) ----------------
__global__ __launch_bounds__(256) void ln1_window_kernel(
        const float* __restrict__ x, const float* __restrict__ g,
        const float* __restrict__ b, u16* __restrict__ out) {
    int row  = blockIdx.x * 4 + (threadIdx.x >> 6);
    int lane = threadIdx.x & 63;
    int win = row / NTOK;
    int n   = row - win * NTOK;
    int bb  = win >> 6;
    int wl  = win & 63;
    int hi  = (wl >> 3) * WS_ + n / WS_;
    int hj  = (wl & 7) * WS_ + n % WS_;
    int sh = hi + SHIFT_; if (sh >= HH) sh -= HH;
    int sw = hj + SHIFT_; if (sw >= WW_) sw -= WW_;
    const float* xr = x + ((size_t)(bb * HH * WW_ + sh * WW_ + sw)) * DIM;
    float v0 = xr[lane], v1 = xr[lane + 64], v2 = xr[lane + 128];
    float s  = wave_sum(v0 + v1 + v2);
    float sq = wave_sum(v0 * v0 + v1 * v1 + v2 * v2);
    float mu  = s * (1.0f / DIM);
    float var = sq * (1.0f / DIM) - mu * mu;
    float r = rsqrtf(var + EPS_);
    u16* orow = out + (size_t)row * DIM;
    orow[lane]       = f2bf((v0 - mu) * r * g[lane]       + b[lane]);
    orow[lane + 64]  = f2bf((v1 - mu) * r * g[lane + 64]  + b[lane + 64]);
    orow[lane + 128] = f2bf((v2 - mu) * r * g[lane + 128] + b[lane + 128]);
}

// ---------------- LN2: fp32 in (residual stream), bf16 out ----------------
__global__ __launch_bounds__(256) void ln2_kernel(
        const float* __restrict__ x, const float* __restrict__ g,
        const float* __restrict__ b, u16* __restrict__ out) {
    int row  = blockIdx.x * 4 + (threadIdx.x >> 6);
    int lane = threadIdx.x & 63;
    const float* xr = x + (size_t)row * DIM;
    float v0 = xr[lane], v1 = xr[lane + 64], v2 = xr[lane + 128];
    float s  = wave_sum(v0 + v1 + v2);
    float sq = wave_sum(v0 * v0 + v1 * v1 + v2 * v2);
    float mu  = s * (1.0f / DIM);
    float var = sq * (1.0f / DIM) - mu * mu;
    float r = rsqrtf(var + EPS_);
    u16* orow = out + (size_t)row * DIM;
    orow[lane]       = f2bf((v0 - mu) * r * g[lane]       + b[lane]);
    orow[lane + 64]  = f2bf((v1 - mu) * r * g[lane + 64]  + b[lane + 64]);
    orow[lane + 128] = f2bf((v2 - mu) * r * g[lane + 128] + b[lane + 128]);
}

// ---------------- MFMA GEMM core ----------------
struct GemmSmem {
    u16 As[BM][LDK];
    u16 Bs[BN][LDK];
};

template<int K>
__device__ __forceinline__ void gemm_core(
        const u16* __restrict__ A, const u16* __restrict__ Bt,
        int m0, int n0, GemmSmem& sm, f32x4 (&acc)[4][4]) {
    int tid  = threadIdx.x;
    int lane = tid & 63;
    int w    = tid >> 6;
    int lrow = lane & 15;
    int lq   = lane >> 4;

    #pragma unroll
    for (int i = 0; i < 4; i++)
        #pragma unroll
        for (int j = 0; j < 4; j++) acc[i][j] = (f32x4){0.f, 0.f, 0.f, 0.f};

    int bn = tid >> 2, bko = (tid & 3) * 8;

    for (int k0 = 0; k0 < K; k0 += BK) {
        uint4 a_ld[4];
        #pragma unroll
        for (int i = 0; i < 4; i++) {
            int c = tid + i * 256;
            int m = c >> 2, ko = (c & 3) * 8;
            a_ld[i] = *(const uint4*)(A + (size_t)(m0 + m) * K + k0 + ko);
        }
        uint4 b_ld = *(const uint4*)(Bt + (size_t)(n0 + bn) * K + k0 + bko);
        __syncthreads();
        #pragma unroll
        for (int i = 0; i < 4; i++) {
            int c = tid + i * 256;
            int m = c >> 2, ko = (c & 3) * 8;
            *(uint4*)&sm.As[m][ko] = a_ld[i];
        }
        *(uint4*)&sm.Bs[bn][bko] = b_ld;
        __syncthreads();
        bf16x8 aF[4], bF[4];
        #pragma unroll
        for (int mt = 0; mt < 4; mt++)
            aF[mt] = *(const bf16x8*)&sm.As[w * 64 + mt * 16 + lrow][lq * 8];
        #pragma unroll
        for (int nt = 0; nt < 4; nt++)
            bF[nt] = *(const bf16x8*)&sm.Bs[nt * 16 + lrow][lq * 8];
        #pragma unroll
        for (int mt = 0; mt < 4; mt++)
            #pragma unroll
            for (int nt = 0; nt < 4; nt++)
                acc[mt][nt] = __builtin_amdgcn_mfma_f32_16x16x32_bf16(
                    aF[mt], bF[nt], acc[mt][nt], 0, 0, 0);
    }
}

// ---------------- GEMM: QKV projection; q,k -> [wh][n][d], v -> transposed [wh][d][64] ------
__global__ __launch_bounds__(256) void gemm_qkv_mfma(
        const u16* __restrict__ Aact, const u16* __restrict__ Bt,
        const float* __restrict__ bias,
        u16* __restrict__ q, u16* __restrict__ k, u16* __restrict__ vt) {
    __shared__ GemmSmem sm;
    f32x4 acc[4][4];
    int m0 = blockIdx.y * BM, n0 = blockIdx.x * BN;
    gemm_core<DIM>(Aact, Bt, m0, n0, sm, acc);
    int lane = threadIdx.x & 63, w = threadIdx.x >> 6;
    int lrow = lane & 15, lq = lane >> 4;
    #pragma unroll
    for (int nt = 0; nt < 4; nt++) {
        int col = n0 + nt * 16 + lrow;
        float bv = bias[col];
        int which = col / DIM;
        int rem   = col - which * DIM;
        int head  = rem >> 5;
        int d     = rem & 31;
        #pragma unroll
        for (int mt = 0; mt < 4; mt++)
            #pragma unroll
            for (int r = 0; r < 4; r++) {
                int row = m0 + w * 64 + mt * 16 + lq * 4 + r;
                int win = row / NTOK;
                int n   = row - win * NTOK;
                size_t wh = (size_t)win * HEADS + head;
                u16 val = f2bf(acc[mt][nt][r] + bv);
                if (which == 0)      q[(wh * NTOK + n) * HDIM + d] = val;
                else if (which == 1) k[(wh * NTOK + n) * HDIM + d] = val;
                else                 vt[(wh * HDIM + d) * 64 + n] = val;
            }
    }
}

// ---------------- MFMA attention: one block per window, one wave per head ----------------
__global__ __launch_bounds__(384) void attn_mfma_kernel(
        const u16* __restrict__ q, const u16* __restrict__ k,
        const u16* __restrict__ vt, const float* __restrict__ tbl,
        u16* __restrict__ attn_out) {
    __shared__ u16 smem[HEADS * 64 * PLD];   // 55296 B; P buffers, later O staging
    int tid  = threadIdx.x;
    int w    = tid >> 6;          // head
    int lane = tid & 63;
    int lrow = lane & 15, lq = lane >> 4;
    int win  = blockIdx.x;
    int wl   = win & 63;
    size_t wh = (size_t)win * HEADS + w;
    u16* Pl = smem + w * 64 * PLD;

    // ---- load Q,K fragments straight from global (A/B layout: [row16][k8 contiguous]) ----
    bf16x8 qf[4], kf[4];
    const u16* qbase = q + wh * NTOK * HDIM;
    const u16* kbase = k + wh * NTOK * HDIM;
    #pragma unroll
    for (int t = 0; t < 4; t++) {
        int row = t * 16 + lrow; if (row > 48) row = 48;   // clamp pads (masked later)
        qf[t] = *(const bf16x8*)(qbase + row * HDIM + lq * 8);
        kf[t] = *(const bf16x8*)(kbase + row * HDIM + lq * 8);
    }

    // ---- S = Q·K^T : 16 mfma (K=32=HDIM, one k-step) ----
    f32x4 sc[4][4];
    #pragma unroll
    for (int mt = 0; mt < 4; mt++)
        #pragma unroll
        for (int nt = 0; nt < 4; nt++) {
            f32x4 z = (f32x4){0.f, 0.f, 0.f, 0.f};
            sc[mt][nt] = __builtin_amdgcn_mfma_f32_16x16x32_bf16(qf[mt], kf[nt], z, 0, 0, 0);
        }

    // ---- scale + bias + mask (fused table), softmax in registers ----
    const float* tb = tbl + (((size_t)wl * HEADS + w) << 12);
    float inv[4][4];
    #pragma unroll
    for (int mt = 0; mt < 4; mt++)
        #pragma unroll
        for (int r = 0; r < 4; r++) {
            int qi = mt * 16 + lq * 4 + r;
            float mx = -3.0e38f;
            #pragma unroll
            for (int nt = 0; nt < 4; nt++) {
                float s = sc[mt][nt][r] * SCALE_ + tb[(qi << 6) + nt * 16 + lrow];
                sc[mt][nt][r] = s;
                mx = fmaxf(mx, s);
            }
            #pragma unroll
            for (int off = 8; off > 0; off >>= 1) mx = fmaxf(mx, __shfl_xor(mx, off, 64));
            float sum = 0.f;
            #pragma unroll
            for (int nt = 0; nt < 4; nt++) {
                float e = __expf(sc[mt][nt][r] - mx);
                sc[mt][nt][r] = e;
                sum += e;
            }
            #pragma unroll
            for (int off = 8; off > 0; off >>= 1) sum += __shfl_xor(sum, off, 64);
            inv[mt][r] = 1.0f / sum;
        }

    // ---- P (unnormalized probs) -> LDS, bf16, row stride PLD ----
    #pragma unroll
    for (int mt = 0; mt < 4; mt++)
        #pragma unroll
        for (int nt = 0; nt < 4; nt++)
            #pragma unroll
            for (int r = 0; r < 4; r++) {
                int qi = mt * 16 + lq * 4 + r;
                int kj = nt * 16 + lrow;
                Pl[qi * PLD + kj] = f2bf(sc[mt][nt][r]);
            }
    __syncthreads();   // order P writes before frag reads (and uniform across waves)

    // ---- O = P·V : V^T frags from global, P A-frags from LDS ----
    const u16* vbase = vt + wh * HDIM * 64;
    bf16x8 vf[2][2];
    #pragma unroll
    for (int nd = 0; nd < 2; nd++)
        #pragma unroll
        for (int ks = 0; ks < 2; ks++)
            vf[nd][ks] = *(const bf16x8*)(vbase + (nd * 16 + lrow) * 64 + ks * 32 + lq * 8);
    f32x4 oc[4][2];
    #pragma unroll
    for (int mt = 0; mt < 4; mt++)
        #pragma unroll
        for (int nd = 0; nd < 2; nd++) oc[mt][nd] = (f32x4){0.f, 0.f, 0.f, 0.f};
    #pragma unroll
    for (int mt = 0; mt < 4; mt++)
        #pragma unroll
        for (int ks = 0; ks < 2; ks++) {
            bf16x8 pf = *(const bf16x8*)&Pl[(mt * 16 + lrow) * PLD + ks * 32 + lq * 8];
            #pragma unroll
            for (int nd = 0; nd < 2; nd++)
                oc[mt][nd] = __builtin_amdgcn_mfma_f32_16x16x32_bf16(pf, vf[nd][ks],
                                                                     oc[mt][nd], 0, 0, 0);
        }

    // ---- stage O into LDS (reuse P region), then fully-coalesced global write ----
    __syncthreads();   // all waves done reading P
    u16* Osh = smem;   // [NTOK][OLD]
    #pragma unroll
    for (int mt = 0; mt < 4; mt++)
        #pragma unroll
        for (int r = 0; r < 4; r++) {
            int row = mt * 16 + lq * 4 + r;
            if (row < NTOK) {
                #pragma unroll
                for (int nd = 0; nd < 2; nd++)
                    Osh[row * OLD + w * HDIM + nd * 16 + lrow] =
                        f2bf(oc[mt][nd][r] * inv[mt][r]);
            }
        }
    __syncthreads();
    u16* obase = attn_out + (size_t)win * NTOK * DIM;
    for (int i = tid; i < NTOK * (DIM / 8); i += 384) {
        int n = i / (DIM / 8), c = i - n * (DIM / 8);
        *(uint4*)(obase + (size_t)n * DIM + c * 8) = *(const uint4*)&Osh[n * OLD + c * 8];
    }
}

// ------- GEMM: proj + window reverse + roll(+3,+3) + residual(fp32 x) -> fp32 x1 -------
__global__ __launch_bounds__(256) void gemm_proj_mfma(
        const u16* __restrict__ Aact, const u16* __restrict__ Bt,
        const float* __restrict__ bias, const float* __restrict__ x,
        float* __restrict__ x1) {
    __shared__ GemmSmem sm;
    f32x4 acc[4][4];
    int m0 = blockIdx.y * BM, n0 = blockIdx.x * BN;
    gemm_core<DIM>(Aact, Bt, m0, n0, sm, acc);
    int lane = threadIdx.x & 63, w = threadIdx.x >> 6;
    int lrow = lane & 15, lq = lane >> 4;
    #pragma unroll
    for (int mt = 0; mt < 4; mt++)
        #pragma unroll
        for (int r = 0; r < 4; r++) {
            int row = m0 + w * 64 + mt * 16 + lq * 4 + r;
            int win = row / NTOK;
            int n   = row - win * NTOK;
            int bb  = win >> 6;
            int wl  = win & 63;
            int hi = (wl >> 3) * WS_ + n / WS_;
            int hj = (wl & 7) * WS_ + n % WS_;
            int dh = hi + SHIFT_; if (dh >= HH) dh -= HH;
            int dw = hj + SHIFT_; if (dw >= WW_) dw -= WW_;
            size_t tok = (size_t)(bb * HH * WW_ + dh * WW_ + dw);
            #pragma unroll
            for (int nt = 0; nt < 4; nt++) {
                int col = n0 + nt * 16 + lrow;
                x1[tok * DIM + col] = x[tok * DIM + col] + acc[mt][nt][r] + bias[col];
            }
        }
}

// ---------------- GEMM: FC1 + exact GELU (bf16 out, chunk-relative rows) ----------------
__global__ __launch_bounds__(256) void gemm_fc1_mfma(
        const u16* __restrict__ Aact, const u16* __restrict__ Bt,
        const float* __restrict__ bias, u16* __restrict__ fc1_out) {
    __shared__ GemmSmem sm;
    f32x4 acc[4][4];
    int m0 = blockIdx.y * BM, n0 = blockIdx.x * BN;
    gemm_core<DIM>(Aact, Bt, m0, n0, sm, acc);
    int lane = threadIdx.x & 63, w = threadIdx.x >> 6;
    int lrow = lane & 15, lq = lane >> 4;
    #pragma unroll
    for (int nt = 0; nt < 4; nt++) {
        int col = n0 + nt * 16 + lrow;
        float bv = bias[col];
        #pragma unroll
        for (int mt = 0; mt < 4; mt++)
            #pragma unroll
            for (int r = 0; r < 4; r++) {
                size_t row = (size_t)(m0 + w * 64 + mt * 16 + lq * 4 + r);
                float val = acc[mt][nt][r] + bv;
                float gel = 0.5f * val * (1.0f + erff(val * 0.70710678118f));
                fc1_out[row * HIDDEN + col] = f2bf(gel);
            }
    }
}

// ---------------- GEMM: FC2 + residual(fp32 x1) -> fp32 out ----------------
__global__ __launch_bounds__(256) void gemm_fc2_mfma(
        const u16* __restrict__ Aact, const u16* __restrict__ Bt,
        const float* __restrict__ bias, const float* __restrict__ x1,
        float* __restrict__ out, int row_off) {
    __shared__ GemmSmem sm;
    f32x4 acc[4][4];
    int m0 = blockIdx.y * BM, n0 = blockIdx.x * BN;
    gemm_core<HIDDEN>(Aact, Bt, m0, n0, sm, acc);
    int lane = threadIdx.x & 63, w = threadIdx.x >> 6;
    int lrow = lane & 15, lq = lane >> 4;
    #pragma unroll
    for (int nt = 0; nt < 4; nt++) {
        int col = n0 + nt * 16 + lrow;
        float bv = bias[col];
        #pragma unroll
        for (int mt = 0; mt < 4; mt++)
            #pragma unroll
            for (int r = 0; r < 4; r++) {
                size_t grow = (size_t)(row_off + m0 + w * 64 + mt * 16 + lq * 4 + r);
                out[grow * DIM + col] = x1[grow * DIM + col] + acc[mt][nt][r] + bv;
            }
    }
}

extern "C" void kernel_launch(void* const* d_in, const int* in_sizes, int n_in,
                              void* d_out, int out_size, void* d_ws, size_t ws_size,
                              hipStream_t stream) {
    const float* x         = (const float*)d_in[0];
    const float* g1        = (const float*)d_in[1];
    const float* b1        = (const float*)d_in[2];
    const float* qkv_w     = (const float*)d_in[3];
    const float* qkv_b     = (const float*)d_in[4];
    const float* proj_w    = (const float*)d_in[5];
    const float* proj_b    = (const float*)d_in[6];
    const float* rel_table = (const float*)d_in[7];
    const float* g2        = (const float*)d_in[8];
    const float* b2        = (const float*)d_in[9];
    const float* fc1_w     = (const float*)d_in[10];
    const float* fc1_b     = (const float*)d_in[11];
    const float* fc2_w     = (const float*)d_in[12];
    const float* fc2_b     = (const float*)d_in[13];
    const float* attn_mask = (const float*)d_in[14];
    float* out = (float*)d_out;

    const size_t S = (size_t)MTOT * DIM;       // 19,267,584 elements
    const size_t VT_SZ = (size_t)B_ * NWIN * HEADS * HDIM * 64;  // 25,165,824 u16
    u16* wsu = (u16*)d_ws;
    // u16-unit layout; peak ~173 MB (proven-safe bound 193 MB)
    u16*   hwin    = wsu;                      // [0,S)      LN1 out -> attn out -> LN2 out
    u16*   qb      = wsu + S;                  // [S,2S)
    u16*   kb      = wsu + 2 * S;              // [2S,3S)
    u16*   vt      = wsu + 3 * S;              // [3S, 3S+VT_SZ)  V^T [wh][d][64]
    u16*   ao      = hwin;                     // attn out overlays LN1 out
    float* x1      = (float*)(wsu + S);        // fp32 residual, overlays qb+kb (dead after attn)
    u16*   fc1_buf = vt;                       // MLP chunk overlays vt (dead after attn)
    u16*   wT      = wsu + 3 * S + VT_SZ;      // bf16 transposed weights
    u16*   qkv_wT  = wT;                       // 110592
    u16*   proj_wT = wT + 110592;              // 36864
    u16*   fc1_wT  = wT + 147456;              // 147456
    u16*   fc2_wT  = wT + 294912;              // 147456
    float* tbl     = (float*)(wT + 442368);    // 64*6*64*64 fp32 = 6.29 MB

    transpose_w_kernel<<<(DIM * 3 * DIM + 255) / 256, 256, 0, stream>>>(qkv_w, qkv_wT, DIM, 3 * DIM);
    transpose_w_kernel<<<(DIM * DIM + 255) / 256, 256, 0, stream>>>(proj_w, proj_wT, DIM, DIM);
    transpose_w_kernel<<<(DIM * HIDDEN + 255) / 256, 256, 0, stream>>>(fc1_w, fc1_wT, DIM, HIDDEN);
    transpose_w_kernel<<<(HIDDEN * DIM + 255) / 256, 256, 0, stream>>>(fc2_w, fc2_wT, HIDDEN, DIM);
    build_tbl_kernel<<<(NWIN * HEADS * 64 * 64) / 256, 256, 0, stream>>>(rel_table, attn_mask, tbl);

    ln1_window_kernel<<<MTOT / 4, 256, 0, stream>>>(x, g1, b1, hwin);
    gemm_qkv_mfma<<<dim3(9, MTOT / BM), 256, 0, stream>>>(hwin, qkv_wT, qkv_b, qb, kb, vt);
    attn_mfma_kernel<<<B_ * NWIN, 384, 0, stream>>>(qb, kb, vt, tbl, ao);
    gemm_proj_mfma<<<dim3(3, MTOT / BM), 256, 0, stream>>>(ao, proj_wT, proj_b, x, x1);
    ln2_kernel<<<MTOT / 4, 256, 0, stream>>>(x1, g2, b2, hwin);
    for (int c = 0; c < 4; c++) {
        const u16* h2c = hwin + (size_t)c * CHUNK_M * DIM;
        gemm_fc1_mfma<<<dim3(12, CHUNK_M / BM), 256, 0, stream>>>(h2c, fc1_wT, fc1_b, fc1_buf);
        gemm_fc2_mfma<<<dim3(3, CHUNK_M / BM), 256, 0, stream>>>(fc1_buf, fc2_wT, fc2_b, x1,
                                                                 out, c * CHUNK_M);
    }
}

// Round 6
// 847.257 us; speedup vs baseline: 1.8156x; 1.2388x over previous
//
#include <hip/hip_runtime.h>
#include <math.h>

// ---- problem constants ----
#define B_      32
#define HH      56
#define WW_     56
#define DIM     192
#define WS_     7
#define SHIFT_  3
#define HEADS   6
#define HDIM    32
#define NTOK    49          // WS*WS
#define NWIN    64          // (H/WS)*(W/WS)
#define HIDDEN  768
#define MTOT    (B_*HH*WW_) // 100352 tokens
#define CHUNK_M 25088       // MTOT/4 for MLP chunking
#define EPS_    1e-5f
#define SCALE_  0.17677669529663687f  // 1/sqrt(32)

// MLP GEMM tiling
#define BM 256
#define BN 64
#define BK 32
#define LDK 40   // padded LDS K-stride

// fused-attention LDS strides (u16 units)
#define ALD 200  // Ash/Qsh/Ksh/Osh row stride (64 rows): 400 B, %16==0, 2-way banks
#define PLD 40   // P row stride (per-head 64 rows)
#define VLD 72   // Vt row stride (192 rows)

typedef unsigned short u16;
typedef __attribute__((ext_vector_type(8))) __bf16 bf16x8;
typedef __attribute__((ext_vector_type(4))) float f32x4;

__device__ __forceinline__ float bf2f(u16 u) {
    union { unsigned int i; float f; } c; c.i = ((unsigned int)u) << 16; return c.f;
}
__device__ __forceinline__ u16 f2bf(float f) {
    union { float f; unsigned int i; } c; c.f = f;
    unsigned int x = c.i;
    return (u16)((x + 0x7FFFu + ((x >> 16) & 1u)) >> 16);  // RNE (finite values)
}

__device__ __forceinline__ float wave_sum(float v) {
    #pragma unroll
    for (int off = 32; off > 0; off >>= 1) v += __shfl_xor(v, off, 64);
    return v;
}

// ---------------- weight convert+transpose: Wt[n*K+k] = bf16(W[k*N+n]) ----------------
__global__ __launch_bounds__(256) void transpose_w_kernel(
        const float* __restrict__ W, u16* __restrict__ Wt, int K, int N) {
    int idx = blockIdx.x * 256 + threadIdx.x;
    if (idx >= K * N) return;
    int n = idx / K, kk = idx - n * K;
    Wt[idx] = f2bf(W[(size_t)kk * N + n]);
}

// ------- fused bias+mask table: tbl[((wl*6+head)*64+qi)*64+kj], pads = -1e30 -------
__global__ __launch_bounds__(256) void build_tbl_kernel(
        const float* __restrict__ rel_table, const float* __restrict__ mask,
        float* __restrict__ tbl) {
    int idx = blockIdx.x * 256 + threadIdx.x;   // < 64*6*4096
    int kj   = idx & 63;
    int qi   = (idx >> 6) & 63;
    int head = (idx >> 12) % 6;
    int wl   = idx / (6 << 12);
    float v;
    if (qi < NTOK && kj < NTOK) {
        int qr = qi / WS_, qc = qi % WS_;
        int kr = kj / WS_, kc = kj % WS_;
        int ri = (qr - kr + 6) * 13 + (qc - kc + 6);
        v = rel_table[ri * HEADS + head] + mask[((size_t)wl * NTOK + qi) * NTOK + kj];
    } else {
        v = -1e30f;
    }
    tbl[idx] = v;
}

// ---------------- LN1 + roll(-3,-3) + window partition (fp32 in, bf16 out) ----------------
__global__ __launch_bounds__(256) void ln1_window_kernel(
        const float* __restrict__ x, const float* __restrict__ g,
        const float* __restrict__ b, u16* __restrict__ out) {
    int row  = blockIdx.x * 4 + (threadIdx.x >> 6);
    int lane = threadIdx.x & 63;
    int win = row / NTOK;
    int n   = row - win * NTOK;
    int bb  = win >> 6;
    int wl  = win & 63;
    int hi  = (wl >> 3) * WS_ + n / WS_;
    int hj  = (wl & 7) * WS_ + n % WS_;
    int sh = hi + SHIFT_; if (sh >= HH) sh -= HH;
    int sw = hj + SHIFT_; if (sw >= WW_) sw -= WW_;
    const float* xr = x + ((size_t)(bb * HH * WW_ + sh * WW_ + sw)) * DIM;
    float v0 = xr[lane], v1 = xr[lane + 64], v2 = xr[lane + 128];
    float s  = wave_sum(v0 + v1 + v2);
    float sq = wave_sum(v0 * v0 + v1 * v1 + v2 * v2);
    float mu  = s * (1.0f / DIM);
    float var = sq * (1.0f / DIM) - mu * mu;
    float r = rsqrtf(var + EPS_);
    u16* orow = out + (size_t)row * DIM;
    orow[lane]       = f2bf((v0 - mu) * r * g[lane]       + b[lane]);
    orow[lane + 64]  = f2bf((v1 - mu) * r * g[lane + 64]  + b[lane + 64]);
    orow[lane + 128] = f2bf((v2 - mu) * r * g[lane + 128] + b[lane + 128]);
}

// ---------------- LN2: fp32 in (residual stream), bf16 out ----------------
__global__ __launch_bounds__(256) void ln2_kernel(
        const float* __restrict__ x, const float* __restrict__ g,
        const float* __restrict__ b, u16* __restrict__ out) {
    int row  = blockIdx.x * 4 + (threadIdx.x >> 6);
    int lane = threadIdx.x & 63;
    const float* xr = x + (size_t)row * DIM;
    float v0 = xr[lane], v1 = xr[lane + 64], v2 = xr[lane + 128];
    float s  = wave_sum(v0 + v1 + v2);
    float sq = wave_sum(v0 * v0 + v1 * v1 + v2 * v2);
    float mu  = s * (1.0f / DIM);
    float var = sq * (1.0f / DIM) - mu * mu;
    float r = rsqrtf(var + EPS_);
    u16* orow = out + (size_t)row * DIM;
    orow[lane]       = f2bf((v0 - mu) * r * g[lane]       + b[lane]);
    orow[lane + 64]  = f2bf((v1 - mu) * r * g[lane + 64]  + b[lane + 64]);
    orow[lane + 128] = f2bf((v2 - mu) * r * g[lane + 128] + b[lane + 128]);
}

// ================= fused window attention: QKV + attn + proj + residual =================
// One block per window (2048), 384 threads = 6 waves = 6 heads.
// LDS: R1 [0,15360) u16: Ash/Qsh/Ksh (64xALD) -> P (6 x 64xPLD) -> Osh (64xALD)
//      Vt [15360, 29184): 192 x VLD
__global__ __launch_bounds__(384) void fused_attn_kernel(
        const u16* __restrict__ hwin, const u16* __restrict__ qkv_wT,
        const float* __restrict__ qkv_b, const u16* __restrict__ proj_wT,
        const float* __restrict__ proj_b, const float* __restrict__ tbl,
        const float* __restrict__ x, float* __restrict__ x1) {
    __shared__ u16 sm[29184];
    u16* R1 = sm;
    u16* Vt = sm + 15360;

    const int tid  = threadIdx.x;
    const int w    = tid >> 6;       // head
    const int lane = tid & 63;
    const int lrow = lane & 15, lq = lane >> 4;
    const int win  = blockIdx.x;
    const int wl   = win & 63, bb = win >> 6;

    // ---- phase 0: stage LN1 window rows (49x192, zero-pad to 64) ----
    {
        const uint4* src = (const uint4*)(hwin + (size_t)win * NTOK * DIM);
        uint4 z; z.x = z.y = z.z = z.w = 0u;
        #pragma unroll
        for (int it = 0; it < 4; it++) {
            int i = tid + it * 384;          // < 1536 = 64*24
            int row = i / 24, c = i - row * 24;
            uint4 v = (row < NTOK) ? src[row * 24 + c] : z;
            *(uint4*)&R1[row * ALD + c * 8] = v;
        }
    }
    __syncthreads();

    // ---- phase 1: QKV projection for this head (W streamed from L2) ----
    f32x4 acc[3][4][2];
    #pragma unroll
    for (int o = 0; o < 3; o++)
        #pragma unroll
        for (int mt = 0; mt < 4; mt++)
            #pragma unroll
            for (int nt = 0; nt < 2; nt++) acc[o][mt][nt] = (f32x4){0.f, 0.f, 0.f, 0.f};

    const u16* bcol[3][2];
    #pragma unroll
    for (int o = 0; o < 3; o++)
        #pragma unroll
        for (int nt = 0; nt < 2; nt++)
            bcol[o][nt] = qkv_wT + (size_t)(o * DIM + w * 32 + nt * 16 + lrow) * DIM + lq * 8;

    #pragma unroll
    for (int ks = 0; ks < 6; ks++) {
        bf16x8 aF[4];
        #pragma unroll
        for (int mt = 0; mt < 4; mt++)
            aF[mt] = *(const bf16x8*)&R1[(mt * 16 + lrow) * ALD + ks * 32 + lq * 8];
        bf16x8 bF[3][2];
        #pragma unroll
        for (int o = 0; o < 3; o++)
            #pragma unroll
            for (int nt = 0; nt < 2; nt++)
                bF[o][nt] = *(const bf16x8*)(bcol[o][nt] + ks * 32);
        #pragma unroll
        for (int o = 0; o < 3; o++)
            #pragma unroll
            for (int mt = 0; mt < 4; mt++)
                #pragma unroll
                for (int nt = 0; nt < 2; nt++)
                    acc[o][mt][nt] = __builtin_amdgcn_mfma_f32_16x16x32_bf16(
                        aF[mt], bF[o][nt], acc[o][mt][nt], 0, 0, 0);
    }
    // biases
    float bias_[3][2];
    #pragma unroll
    for (int o = 0; o < 3; o++)
        #pragma unroll
        for (int nt = 0; nt < 2; nt++)
            bias_[o][nt] = qkv_b[o * DIM + w * 32 + nt * 16 + lrow];
    #pragma unroll
    for (int o = 0; o < 3; o++)
        #pragma unroll
        for (int mt = 0; mt < 4; mt++)
            #pragma unroll
            for (int nt = 0; nt < 2; nt++)
                #pragma unroll
                for (int r = 0; r < 4; r++) acc[o][mt][nt][r] += bias_[o][nt];

    __syncthreads();   // Ash dead; R1 becomes Q/K staging (wave-local col stripes)

    // ---- phase 2: stage Q (C-layout -> A-frag), then K (-> B-frag), then V^T ----
    #pragma unroll
    for (int mt = 0; mt < 4; mt++)
        #pragma unroll
        for (int nt = 0; nt < 2; nt++)
            #pragma unroll
            for (int r = 0; r < 4; r++)
                R1[(mt * 16 + lq * 4 + r) * ALD + w * 32 + nt * 16 + lrow] =
                    f2bf(acc[0][mt][nt][r]);
    bf16x8 qf[4];
    #pragma unroll
    for (int mt = 0; mt < 4; mt++)
        qf[mt] = *(const bf16x8*)&R1[(mt * 16 + lrow) * ALD + w * 32 + lq * 8];

    #pragma unroll
    for (int mt = 0; mt < 4; mt++)
        #pragma unroll
        for (int nt = 0; nt < 2; nt++)
            #pragma unroll
            for (int r = 0; r < 4; r++)
                R1[(mt * 16 + lq * 4 + r) * ALD + w * 32 + nt * 16 + lrow] =
                    f2bf(acc[1][mt][nt][r]);
    bf16x8 kf[4];
    #pragma unroll
    for (int nt = 0; nt < 4; nt++)
        kf[nt] = *(const bf16x8*)&R1[(nt * 16 + lrow) * ALD + w * 32 + lq * 8];

    #pragma unroll
    for (int mt = 0; mt < 4; mt++)
        #pragma unroll
        for (int nt = 0; nt < 2; nt++)
            #pragma unroll
            for (int r = 0; r < 4; r++)
                Vt[(w * 32 + nt * 16 + lrow) * VLD + mt * 16 + lq * 4 + r] =
                    f2bf(acc[2][mt][nt][r]);

    // ---- phase 3: S = Q.K^T (16 mfma), softmax in registers ----
    f32x4 sc[4][4];
    #pragma unroll
    for (int mt = 0; mt < 4; mt++)
        #pragma unroll
        for (int nt = 0; nt < 4; nt++) {
            f32x4 z = (f32x4){0.f, 0.f, 0.f, 0.f};
            sc[mt][nt] = __builtin_amdgcn_mfma_f32_16x16x32_bf16(qf[mt], kf[nt], z, 0, 0, 0);
        }
    const float* tb = tbl + (((size_t)wl * HEADS + w) << 12);
    float inv[4][4];
    #pragma unroll
    for (int mt = 0; mt < 4; mt++)
        #pragma unroll
        for (int r = 0; r < 4; r++) {
            int qi = mt * 16 + lq * 4 + r;
            float mx = -3.0e38f;
            #pragma unroll
            for (int nt = 0; nt < 4; nt++) {
                float s = sc[mt][nt][r] * SCALE_ + tb[(qi << 6) + nt * 16 + lrow];
                sc[mt][nt][r] = s;
                mx = fmaxf(mx, s);
            }
            #pragma unroll
            for (int off = 8; off > 0; off >>= 1) mx = fmaxf(mx, __shfl_xor(mx, off, 64));
            float sum = 0.f;
            #pragma unroll
            for (int nt = 0; nt < 4; nt++) {
                float e = __expf(sc[mt][nt][r] - mx);
                sc[mt][nt][r] = e;
                sum += e;
            }
            #pragma unroll
            for (int off = 8; off > 0; off >>= 1) sum += __shfl_xor(sum, off, 64);
            inv[mt][r] = 1.0f / sum;
        }

    // ---- phase 4: O = P.V (per-head P slot in R1, two 32-token k-chunks) ----
    u16* Pl = R1 + w * (64 * PLD);
    f32x4 oc[4][2];
    #pragma unroll
    for (int mt = 0; mt < 4; mt++)
        #pragma unroll
        for (int nd = 0; nd < 2; nd++) oc[mt][nd] = (f32x4){0.f, 0.f, 0.f, 0.f};
    #pragma unroll
    for (int ks = 0; ks < 2; ks++) {
        #pragma unroll
        for (int mt = 0; mt < 4; mt++)
            #pragma unroll
            for (int ntl = 0; ntl < 2; ntl++)
                #pragma unroll
                for (int r = 0; r < 4; r++)
                    Pl[(mt * 16 + lq * 4 + r) * PLD + ntl * 16 + lrow] =
                        f2bf(sc[mt][ks * 2 + ntl][r]);
        bf16x8 vf[2];
        #pragma unroll
        for (int nd = 0; nd < 2; nd++)
            vf[nd] = *(const bf16x8*)&Vt[(w * 32 + nd * 16 + lrow) * VLD + ks * 32 + lq * 8];
        #pragma unroll
        for (int mt = 0; mt < 4; mt++) {
            bf16x8 pf = *(const bf16x8*)&Pl[(mt * 16 + lrow) * PLD + lq * 8];
            #pragma unroll
            for (int nd = 0; nd < 2; nd++)
                oc[mt][nd] = __builtin_amdgcn_mfma_f32_16x16x32_bf16(pf, vf[nd],
                                                                     oc[mt][nd], 0, 0, 0);
        }
    }
    __syncthreads();   // all P reads done; R1 becomes Osh

    // ---- phase 5: stage O (normalized) as 64x192 for proj A-frags ----
    #pragma unroll
    for (int mt = 0; mt < 4; mt++)
        #pragma unroll
        for (int nd = 0; nd < 2; nd++)
            #pragma unroll
            for (int r = 0; r < 4; r++)
                R1[(mt * 16 + lq * 4 + r) * ALD + w * 32 + nd * 16 + lrow] =
                    f2bf(oc[mt][nd][r] * inv[mt][r]);
    __syncthreads();

    // ---- phase 6: proj GEMM (K=192) + roll/reverse + residual -> x1 ----
    f32x4 pacc[4][2];
    #pragma unroll
    for (int mt = 0; mt < 4; mt++)
        #pragma unroll
        for (int nt = 0; nt < 2; nt++) pacc[mt][nt] = (f32x4){0.f, 0.f, 0.f, 0.f};
    const u16* pcol[2];
    #pragma unroll
    for (int nt = 0; nt < 2; nt++)
        pcol[nt] = proj_wT + (size_t)(w * 32 + nt * 16 + lrow) * DIM + lq * 8;
    #pragma unroll
    for (int ks = 0; ks < 6; ks++) {
        bf16x8 af[4];
        #pragma unroll
        for (int mt = 0; mt < 4; mt++)
            af[mt] = *(const bf16x8*)&R1[(mt * 16 + lrow) * ALD + ks * 32 + lq * 8];
        bf16x8 pb[2];
        #pragma unroll
        for (int nt = 0; nt < 2; nt++) pb[nt] = *(const bf16x8*)(pcol[nt] + ks * 32);
        #pragma unroll
        for (int mt = 0; mt < 4; mt++)
            #pragma unroll
            for (int nt = 0; nt < 2; nt++)
                pacc[mt][nt] = __builtin_amdgcn_mfma_f32_16x16x32_bf16(
                    af[mt], pb[nt], pacc[mt][nt], 0, 0, 0);
    }
    float pbias[2];
    #pragma unroll
    for (int nt = 0; nt < 2; nt++) pbias[nt] = proj_b[w * 32 + nt * 16 + lrow];
    #pragma unroll
    for (int mt = 0; mt < 4; mt++)
        #pragma unroll
        for (int r = 0; r < 4; r++) {
            int n = mt * 16 + lq * 4 + r;
            if (n < NTOK) {
                int hi = (wl >> 3) * WS_ + n / WS_;
                int hj = (wl & 7) * WS_ + n % WS_;
                int dh = hi + SHIFT_; if (dh >= HH) dh -= HH;
                int dw = hj + SHIFT_; if (dw >= WW_) dw -= WW_;
                size_t tok = (size_t)(bb * HH * WW_ + dh * WW_ + dw);
                #pragma unroll
                for (int nt = 0; nt < 2; nt++) {
                    int col = w * 32 + nt * 16 + lrow;
                    x1[tok * DIM + col] = x[tok * DIM + col] + pacc[mt][nt][r] + pbias[nt];
                }
            }
        }
}

// ---------------- MLP MFMA GEMM core (unchanged from round 5) ----------------
struct GemmSmem {
    u16 As[BM][LDK];
    u16 Bs[BN][LDK];
};

template<int K>
__device__ __forceinline__ void gemm_core(
        const u16* __restrict__ A, const u16* __restrict__ Bt,
        int m0, int n0, GemmSmem& sm, f32x4 (&acc)[4][4]) {
    int tid  = threadIdx.x;
    int lane = tid & 63;
    int w    = tid >> 6;
    int lrow = lane & 15;
    int lq   = lane >> 4;
    #pragma unroll
    for (int i = 0; i < 4; i++)
        #pragma unroll
        for (int j = 0; j < 4; j++) acc[i][j] = (f32x4){0.f, 0.f, 0.f, 0.f};
    int bn = tid >> 2, bko = (tid & 3) * 8;
    for (int k0 = 0; k0 < K; k0 += BK) {
        uint4 a_ld[4];
        #pragma unroll
        for (int i = 0; i < 4; i++) {
            int c = tid + i * 256;
            int m = c >> 2, ko = (c & 3) * 8;
            a_ld[i] = *(const uint4*)(A + (size_t)(m0 + m) * K + k0 + ko);
        }
        uint4 b_ld = *(const uint4*)(Bt + (size_t)(n0 + bn) * K + k0 + bko);
        __syncthreads();
        #pragma unroll
        for (int i = 0; i < 4; i++) {
            int c = tid + i * 256;
            int m = c >> 2, ko = (c & 3) * 8;
            *(uint4*)&sm.As[m][ko] = a_ld[i];
        }
        *(uint4*)&sm.Bs[bn][bko] = b_ld;
        __syncthreads();
        bf16x8 aF[4], bF[4];
        #pragma unroll
        for (int mt = 0; mt < 4; mt++)
            aF[mt] = *(const bf16x8*)&sm.As[w * 64 + mt * 16 + lrow][lq * 8];
        #pragma unroll
        for (int nt = 0; nt < 4; nt++)
            bF[nt] = *(const bf16x8*)&sm.Bs[nt * 16 + lrow][lq * 8];
        #pragma unroll
        for (int mt = 0; mt < 4; mt++)
            #pragma unroll
            for (int nt = 0; nt < 4; nt++)
                acc[mt][nt] = __builtin_amdgcn_mfma_f32_16x16x32_bf16(
                    aF[mt], bF[nt], acc[mt][nt], 0, 0, 0);
    }
}

// ---------------- GEMM: FC1 + exact GELU (bf16 out, chunk-relative rows) ----------------
__global__ __launch_bounds__(256) void gemm_fc1_mfma(
        const u16* __restrict__ Aact, const u16* __restrict__ Bt,
        const float* __restrict__ bias, u16* __restrict__ fc1_out) {
    __shared__ GemmSmem sm;
    f32x4 acc[4][4];
    int m0 = blockIdx.y * BM, n0 = blockIdx.x * BN;
    gemm_core<DIM>(Aact, Bt, m0, n0, sm, acc);
    int lane = threadIdx.x & 63, w = threadIdx.x >> 6;
    int lrow = lane & 15, lq = lane >> 4;
    #pragma unroll
    for (int nt = 0; nt < 4; nt++) {
        int col = n0 + nt * 16 + lrow;
        float bv = bias[col];
        #pragma unroll
        for (int mt = 0; mt < 4; mt++)
            #pragma unroll
            for (int r = 0; r < 4; r++) {
                size_t row = (size_t)(m0 + w * 64 + mt * 16 + lq * 4 + r);
                float val = acc[mt][nt][r] + bv;
                float gel = 0.5f * val * (1.0f + erff(val * 0.70710678118f));
                fc1_out[row * HIDDEN + col] = f2bf(gel);
            }
    }
}

// ---------------- GEMM: FC2 + residual(fp32 x1) -> fp32 out ----------------
__global__ __launch_bounds__(256) void gemm_fc2_mfma(
        const u16* __restrict__ Aact, const u16* __restrict__ Bt,
        const float* __restrict__ bias, const float* __restrict__ x1,
        float* __restrict__ out, int row_off) {
    __shared__ GemmSmem sm;
    f32x4 acc[4][4];
    int m0 = blockIdx.y * BM, n0 = blockIdx.x * BN;
    gemm_core<HIDDEN>(Aact, Bt, m0, n0, sm, acc);
    int lane = threadIdx.x & 63, w = threadIdx.x >> 6;
    int lrow = lane & 15, lq = lane >> 4;
    #pragma unroll
    for (int nt = 0; nt < 4; nt++) {
        int col = n0 + nt * 16 + lrow;
        float bv = bias[col];
        #pragma unroll
        for (int mt = 0; mt < 4; mt++)
            #pragma unroll
            for (int r = 0; r < 4; r++) {
                size_t grow = (size_t)(row_off + m0 + w * 64 + mt * 16 + lq * 4 + r);
                out[grow * DIM + col] = x1[grow * DIM + col] + acc[mt][nt][r] + bv;
            }
    }
}

extern "C" void kernel_launch(void* const* d_in, const int* in_sizes, int n_in,
                              void* d_out, int out_size, void* d_ws, size_t ws_size,
                              hipStream_t stream) {
    const float* x         = (const float*)d_in[0];
    const float* g1        = (const float*)d_in[1];
    const float* b1        = (const float*)d_in[2];
    const float* qkv_w     = (const float*)d_in[3];
    const float* qkv_b     = (const float*)d_in[4];
    const float* proj_w    = (const float*)d_in[5];
    const float* proj_b    = (const float*)d_in[6];
    const float* rel_table = (const float*)d_in[7];
    const float* g2        = (const float*)d_in[8];
    const float* b2        = (const float*)d_in[9];
    const float* fc1_w     = (const float*)d_in[10];
    const float* fc1_b     = (const float*)d_in[11];
    const float* fc2_w     = (const float*)d_in[12];
    const float* fc2_b     = (const float*)d_in[13];
    const float* attn_mask = (const float*)d_in[14];
    float* out = (float*)d_out;

    const size_t S = (size_t)MTOT * DIM;       // 19,267,584 elements
    u16* wsu = (u16*)d_ws;
    // u16-unit layout; peak ~161 MB (proven-safe bound 193 MB)
    u16*   hwin    = wsu;                      // [0,S)    LN1 out -> LN2 out
    float* x1      = (float*)(wsu + S);        // [S,3S)   fp32 residual stream
    u16*   fc1_buf = wsu + 3 * S;              // [3S,4S)  MLP chunk (25088x768 bf16 == S)
    u16*   wT      = wsu + 4 * S;              // bf16 transposed weights
    u16*   qkv_wT  = wT;                       // 110592
    u16*   proj_wT = wT + 110592;              // 36864
    u16*   fc1_wT  = wT + 147456;              // 147456
    u16*   fc2_wT  = wT + 294912;              // 147456
    float* tbl     = (float*)(wT + 442368);    // 64*6*64*64 fp32 = 6.29 MB

    transpose_w_kernel<<<(DIM * 3 * DIM + 255) / 256, 256, 0, stream>>>(qkv_w, qkv_wT, DIM, 3 * DIM);
    transpose_w_kernel<<<(DIM * DIM + 255) / 256, 256, 0, stream>>>(proj_w, proj_wT, DIM, DIM);
    transpose_w_kernel<<<(DIM * HIDDEN + 255) / 256, 256, 0, stream>>>(fc1_w, fc1_wT, DIM, HIDDEN);
    transpose_w_kernel<<<(HIDDEN * DIM + 255) / 256, 256, 0, stream>>>(fc2_w, fc2_wT, HIDDEN, DIM);
    build_tbl_kernel<<<(NWIN * HEADS * 64 * 64) / 256, 256, 0, stream>>>(rel_table, attn_mask, tbl);

    ln1_window_kernel<<<MTOT / 4, 256, 0, stream>>>(x, g1, b1, hwin);
    fused_attn_kernel<<<B_ * NWIN, 384, 0, stream>>>(hwin, qkv_wT, qkv_b, proj_wT, proj_b,
                                                     tbl, x, x1);
    ln2_kernel<<<MTOT / 4, 256, 0, stream>>>(x1, g2, b2, hwin);
    for (int c = 0; c < 4; c++) {
        const u16* h2c = hwin + (size_t)c * CHUNK_M * DIM;
        gemm_fc1_mfma<<<dim3(12, CHUNK_M / BM), 256, 0, stream>>>(h2c, fc1_wT, fc1_b, fc1_buf);
        gemm_fc2_mfma<<<dim3(3, CHUNK_M / BM), 256, 0, stream>>>(fc1_buf, fc2_wT, fc2_b, x1,
                                                                 out, c * CHUNK_M);
    }
}